// Round 1
// baseline (1106.971 us; speedup 1.0000x reference)
//
#include <hip/hip_runtime.h>
#include <math.h>

// Problem constants
// x:[2,256,256,512] f32 -> out:[2,256,128,256] f32
// Planes: p = 2m (Re), 2m+1 (Im), m = 0..127 (m=128 contributes exactly 0 since wmat_hi[128,l<128,:]=0)

#define ROWS_HI 131072   // B*C*H_HI
#define ROWS_LO 65536    // B*C*H_LO
#define NPL 256          // 2*128 planes

// ws layout (float offsets)
#define OFF_F   0                      // DFT twiddles F[w][p], 512*256
#define OFF_FI  131072                 // iDFT table Fi[p][w], 256*256
#define OFF_ST  196608                 // GN stats, 128 floats (sum,sumsq per b*32+g)
#define OFF_X   196736                 // X planes [256][131072] (later reused for g planes [256][65536])
#define OFF_Y2  33751168               // flm planes [256][65536] (later reused for y [65536][256])
// total ws need = 33,751,168 + 16,777,216 floats = ~202 MB

__global__ __launch_bounds__(256) void k_tables(float* __restrict__ ws){
  int idx = blockIdx.x*256 + threadIdx.x;
  if (idx < 512*256){
    int w = idx >> 8;
    int p = idx & 255;
    int m = p >> 1;
    int pr = (m*w) & 511;
    float ang = (float)pr * (float)(2.0*M_PI/512.0);
    float s, c; sincosf(ang, &s, &c);
    const float S = (float)(2.0*M_PI/512.0);
    ws[OFF_F + idx] = (p & 1) ? (-S*s) : (S*c);
  }
  int i2 = idx - 512*256;
  if (i2 >= 0 && i2 < 256*256){
    int kp = i2 >> 8;
    int w  = i2 & 255;
    int m  = kp >> 1;
    float eps = (m == 0) ? 1.f : 2.f;
    int pr = (m*w) & 255;
    float ang = (float)pr * (float)(2.0*M_PI/256.0);
    float s, c; sincosf(ang, &s, &c);
    ws[OFF_FI + i2] = (kp & 1) ? (-eps*s) : (eps*c);
  }
  int i3 = idx - (512*256 + 256*256);
  if (i3 >= 0 && i3 < 128) ws[OFF_ST + i3] = 0.f;
}

// DFT: X[p][row] = sum_w x[row][w] * F[w][p].  M=131072, N=256, K=512.
// Tile 128x128, micro 8x8. tr = row lane (fast, for coalesced plane stores), tn = col group.
__global__ __launch_bounds__(256) void k_dft(const float* __restrict__ x,
                                             const float* __restrict__ F,
                                             float* __restrict__ Xpl){
  __shared__ float As[16][132];
  __shared__ float Bs[16][132];
  const int tid = threadIdx.x;
  const int tr = tid & 15;
  const int tn = tid >> 4;
  const int row0 = blockIdx.x * 128;
  const int n0 = blockIdx.y * 128;
  float acc[8][8];
#pragma unroll
  for (int i=0;i<8;++i)
#pragma unroll
    for (int j=0;j<8;++j) acc[i][j]=0.f;

  for (int k0=0;k0<512;k0+=16){
#pragma unroll
    for (int s=0;s<2;++s){
      int id = s*256 + tid;
      int row = id >> 2, kq = (id & 3) * 4;
      float4 v = *(const float4*)(x + (row0+row)*512 + k0 + kq);
      As[kq+0][row]=v.x; As[kq+1][row]=v.y; As[kq+2][row]=v.z; As[kq+3][row]=v.w;
    }
#pragma unroll
    for (int s=0;s<2;++s){
      int id = s*256 + tid;
      int kb = id >> 5, nb = (id & 31)*4;
      *(float4*)&Bs[kb][nb] = *(const float4*)(F + (k0+kb)*256 + n0 + nb);
    }
    __syncthreads();
#pragma unroll
    for (int kk=0;kk<16;++kk){
      float a[8], b[8];
#pragma unroll
      for (int i=0;i<8;++i) a[i] = As[kk][tr + 16*i];
      float4 b0 = *(const float4*)&Bs[kk][tn*4];
      float4 b1 = *(const float4*)&Bs[kk][64 + tn*4];
      b[0]=b0.x;b[1]=b0.y;b[2]=b0.z;b[3]=b0.w;b[4]=b1.x;b[5]=b1.y;b[6]=b1.z;b[7]=b1.w;
#pragma unroll
      for (int i=0;i<8;++i)
#pragma unroll
        for (int j=0;j<8;++j) acc[i][j] = fmaf(a[i], b[j], acc[i][j]);
    }
    __syncthreads();
  }
#pragma unroll
  for (int j=0;j<8;++j){
    int col = (j<4) ? (tn*4+j) : (64 + tn*4 + j - 4);
    float* dst = Xpl + (n0+col)*ROWS_HI + row0 + tr;
#pragma unroll
    for (int i=0;i<8;++i) dst[16*i] = acc[i][j];
  }
}

// Leg1: flm[p][bc][l] = sum_k X[p][bc][k] * wmat[m][l][k].  Per plane: M=512,N=128,K=256. Tile 64x64, micro 4x4.
__global__ __launch_bounds__(256) void k_leg1(const float* __restrict__ Xpl,
                                              const float* __restrict__ wmat,
                                              float* __restrict__ flm){
  const int p = blockIdx.z;
  const int m = p >> 1;
  const int bc0 = blockIdx.x * 64;
  const int l0 = blockIdx.y * 64;
  const int tid = threadIdx.x;
  const int tn = tid & 15;   // l lane (fast, coalesced store)
  const int tr = tid >> 4;   // bc group (rows tr*4..tr*4+3)
  if (m >= l0 + 64){ // whole tile is zero (P_l^m = 0 for l < m)
    float4 z = make_float4(0.f,0.f,0.f,0.f);
#pragma unroll
    for (int i=0;i<4;++i)
      *(float4*)(flm + p*ROWS_LO + (bc0 + tr*4 + i)*128 + l0 + tn*4) = z;
    return;
  }
  __shared__ float As[16][68];
  __shared__ float Bs[16][68];
  float acc[4][4];
#pragma unroll
  for (int i=0;i<4;++i)
#pragma unroll
    for (int j=0;j<4;++j) acc[i][j]=0.f;

  for (int k0=0;k0<256;k0+=16){
    { // A: X plane, 64 rows x 16 k, transpose into As[k][row]
      int row = tid >> 2, kq = (tid & 3)*4;
      float4 v = *(const float4*)(Xpl + p*ROWS_HI + (bc0+row)*256 + k0 + kq);
      As[kq+0][row]=v.x; As[kq+1][row]=v.y; As[kq+2][row]=v.z; As[kq+3][row]=v.w;
    }
    { // B: wmat[m][l][k], 64 l x 16 k, transpose into Bs[k][l]
      int l = tid >> 2, kq = (tid & 3)*4;
      float4 v = *(const float4*)(wmat + m*32768 + (l0+l)*256 + k0 + kq);
      Bs[kq+0][l]=v.x; Bs[kq+1][l]=v.y; Bs[kq+2][l]=v.z; Bs[kq+3][l]=v.w;
    }
    __syncthreads();
#pragma unroll
    for (int kk=0;kk<16;++kk){
      float4 a = *(const float4*)&As[kk][tr*4];
      float4 b = *(const float4*)&Bs[kk][tn*4];
      float av[4]={a.x,a.y,a.z,a.w}, bv[4]={b.x,b.y,b.z,b.w};
#pragma unroll
      for (int i=0;i<4;++i)
#pragma unroll
        for (int j=0;j<4;++j) acc[i][j] = fmaf(av[i], bv[j], acc[i][j]);
    }
    __syncthreads();
  }
#pragma unroll
  for (int i=0;i<4;++i){
    float4 v = make_float4(acc[i][0],acc[i][1],acc[i][2],acc[i][3]);
    *(float4*)(flm + p*ROWS_LO + (bc0 + tr*4 + i)*128 + l0 + tn*4) = v;
  }
}

// Leg2: g[p][bc][k'] = sum_l flm[p][bc][l] * pct[m][l][k'].  Per plane: M=512,N=128,K=128 (l starts at m).
__global__ __launch_bounds__(256) void k_leg2(const float* __restrict__ flm,
                                              const float* __restrict__ pct,
                                              float* __restrict__ g){
  const int p = blockIdx.z;
  const int m = p >> 1;
  const int bc0 = blockIdx.x * 64;
  const int n0 = blockIdx.y * 64;
  const int tid = threadIdx.x;
  const int tn = tid & 15;
  const int tr = tid >> 4;
  __shared__ float As[16][68];
  __shared__ float Bs[16][68];
  float acc[4][4];
#pragma unroll
  for (int i=0;i<4;++i)
#pragma unroll
    for (int j=0;j<4;++j) acc[i][j]=0.f;

  for (int l0c=(m>>4)*16; l0c<128; l0c+=16){
    { // A: flm plane, 64 rows x 16 l, transpose into As[l][row]
      int row = tid >> 2, lq = (tid & 3)*4;
      float4 v = *(const float4*)(flm + p*ROWS_LO + (bc0+row)*128 + l0c + lq);
      As[lq+0][row]=v.x; As[lq+1][row]=v.y; As[lq+2][row]=v.z; As[lq+3][row]=v.w;
    }
    { // B: pct[m][l][k'], natural layout, 16 l x 64 k'
      int lb = tid >> 4, nq = (tid & 15)*4;
      *(float4*)&Bs[lb][nq] = *(const float4*)(pct + m*16384 + (l0c+lb)*128 + n0 + nq);
    }
    __syncthreads();
#pragma unroll
    for (int kk=0;kk<16;++kk){
      float4 a = *(const float4*)&As[kk][tr*4];
      float4 b = *(const float4*)&Bs[kk][tn*4];
      float av[4]={a.x,a.y,a.z,a.w}, bv[4]={b.x,b.y,b.z,b.w};
#pragma unroll
      for (int i=0;i<4;++i)
#pragma unroll
        for (int j=0;j<4;++j) acc[i][j] = fmaf(av[i], bv[j], acc[i][j]);
    }
    __syncthreads();
  }
#pragma unroll
  for (int i=0;i<4;++i){
    float4 v = make_float4(acc[i][0],acc[i][1],acc[i][2],acc[i][3]);
    *(float4*)(g + p*ROWS_LO + (bc0 + tr*4 + i)*128 + n0 + tn*4) = v;
  }
}

// iDFT: y[r][w] = sum_p g[p][r] * Fi[p][w].  M=65536, N=256, K=256. Tile 128x128, micro 8x8.
__global__ __launch_bounds__(256) void k_idft(const float* __restrict__ g,
                                              const float* __restrict__ Fi,
                                              float* __restrict__ y){
  __shared__ float As[16][132];
  __shared__ float Bs[16][132];
  const int tid = threadIdx.x;
  const int tn = tid & 15;   // w lane (fast, coalesced y store)
  const int tr = tid >> 4;   // row group (rows tr+16i)
  const int r0 = blockIdx.x * 128;
  const int w0 = blockIdx.y * 128;
  float acc[8][8];
#pragma unroll
  for (int i=0;i<8;++i)
#pragma unroll
    for (int j=0;j<8;++j) acc[i][j]=0.f;

  for (int k0=0;k0<256;k0+=16){
#pragma unroll
    for (int s=0;s<2;++s){ // A: g planes are column-major already -> natural loads
      int id = s*256 + tid;
      int kp = id >> 5, rq = (id & 31)*4;
      *(float4*)&As[kp][rq] = *(const float4*)(g + (k0+kp)*ROWS_LO + r0 + rq);
    }
#pragma unroll
    for (int s=0;s<2;++s){
      int id = s*256 + tid;
      int kp = id >> 5, nb = (id & 31)*4;
      *(float4*)&Bs[kp][nb] = *(const float4*)(Fi + (k0+kp)*256 + w0 + nb);
    }
    __syncthreads();
#pragma unroll
    for (int kk=0;kk<16;++kk){
      float a[8], b[8];
#pragma unroll
      for (int i=0;i<8;++i) a[i] = As[kk][tr + 16*i];
      float4 b0 = *(const float4*)&Bs[kk][tn*4];
      float4 b1 = *(const float4*)&Bs[kk][64 + tn*4];
      b[0]=b0.x;b[1]=b0.y;b[2]=b0.z;b[3]=b0.w;b[4]=b1.x;b[5]=b1.y;b[6]=b1.z;b[7]=b1.w;
#pragma unroll
      for (int i=0;i<8;++i)
#pragma unroll
        for (int j=0;j<8;++j) acc[i][j] = fmaf(a[i], b[j], acc[i][j]);
    }
    __syncthreads();
  }
#pragma unroll
  for (int i=0;i<8;++i){
    int r = r0 + tr + 16*i;
    *(float4*)(y + r*256 + w0 + tn*4)      = make_float4(acc[i][0],acc[i][1],acc[i][2],acc[i][3]);
    *(float4*)(y + r*256 + w0 + 64 + tn*4) = make_float4(acc[i][4],acc[i][5],acc[i][6],acc[i][7]);
  }
}

// Conv: h[b][o][s] = sum_c W[o][c]*y[b][c][s] + bias[o].  Per b: M=256, N=32768, K=256. Tile 128x128.
__global__ __launch_bounds__(256) void k_conv(const float* __restrict__ y,
                                              const float* __restrict__ Wc,
                                              const float* __restrict__ bias,
                                              float* __restrict__ out){
  __shared__ float As[16][132];
  __shared__ float Bs[16][132];
  const int tid = threadIdx.x;
  const int tn = tid & 15;   // s lane
  const int tr = tid >> 4;   // o group
  const int s0 = blockIdx.x * 128;
  const int o0 = blockIdx.y * 128;
  const int b  = blockIdx.z;
  float acc[8][8];
#pragma unroll
  for (int i=0;i<8;++i)
#pragma unroll
    for (int j=0;j<8;++j) acc[i][j]=0.f;

  for (int c0=0;c0<256;c0+=16){
#pragma unroll
    for (int s=0;s<2;++s){ // A: conv_w [o][c] -> transpose As[c][o]
      int id = s*256 + tid;
      int o = id >> 2, cq = (id & 3)*4;
      float4 v = *(const float4*)(Wc + (o0+o)*256 + c0 + cq);
      As[cq+0][o]=v.x; As[cq+1][o]=v.y; As[cq+2][o]=v.z; As[cq+3][o]=v.w;
    }
#pragma unroll
    for (int s=0;s<2;++s){ // B: y[b][c][s] natural
      int id = s*256 + tid;
      int cb = id >> 5, sq = (id & 31)*4;
      *(float4*)&Bs[cb][sq] = *(const float4*)(y + b*8388608 + (c0+cb)*32768 + s0 + sq);
    }
    __syncthreads();
#pragma unroll
    for (int kk=0;kk<16;++kk){
      float a[8], bb[8];
#pragma unroll
      for (int i=0;i<8;++i) a[i] = As[kk][tr + 16*i];
      float4 b0 = *(const float4*)&Bs[kk][tn*4];
      float4 b1 = *(const float4*)&Bs[kk][64 + tn*4];
      bb[0]=b0.x;bb[1]=b0.y;bb[2]=b0.z;bb[3]=b0.w;bb[4]=b1.x;bb[5]=b1.y;bb[6]=b1.z;bb[7]=b1.w;
#pragma unroll
      for (int i=0;i<8;++i)
#pragma unroll
        for (int j=0;j<8;++j) acc[i][j] = fmaf(a[i], bb[j], acc[i][j]);
    }
    __syncthreads();
  }
#pragma unroll
  for (int i=0;i<8;++i){
    int o = o0 + tr + 16*i;
    float bv = bias[o];
    float* dst = out + (b*256 + o)*32768 + s0;
    *(float4*)(dst + tn*4)      = make_float4(acc[i][0]+bv,acc[i][1]+bv,acc[i][2]+bv,acc[i][3]+bv);
    *(float4*)(dst + 64 + tn*4) = make_float4(acc[i][4]+bv,acc[i][5]+bv,acc[i][6]+bv,acc[i][7]+bv);
  }
}

// GN stats: per (b,g) contiguous 262144 floats of h. 32 blocks per group, atomic partial sums.
__global__ __launch_bounds__(256) void k_stats(const float* __restrict__ h,
                                               float* __restrict__ stats){
  const int bg = blockIdx.y;
  const int j  = blockIdx.x;
  const int t  = threadIdx.x;
  const float* base = h + bg*262144 + j*8192;
  float s = 0.f, ss = 0.f;
#pragma unroll
  for (int i=0;i<8;++i){
    float4 v = *(const float4*)(base + i*1024 + t*4);
    s  += v.x + v.y + v.z + v.w;
    ss += v.x*v.x + v.y*v.y + v.z*v.z + v.w*v.w;
  }
#pragma unroll
  for (int off=32; off>0; off>>=1){
    s  += __shfl_down(s, off, 64);
    ss += __shfl_down(ss, off, 64);
  }
  __shared__ float red[8];
  int wid = t >> 6;
  if ((t & 63) == 0){ red[wid*2] = s; red[wid*2+1] = ss; }
  __syncthreads();
  if (t == 0){
    float S  = red[0]+red[2]+red[4]+red[6];
    float SS = red[1]+red[3]+red[5]+red[7];
    atomicAdd(&stats[bg*2+0], S);
    atomicAdd(&stats[bg*2+1], SS);
  }
}

// Normalize + affine + exact GELU, in place on d_out.
__global__ __launch_bounds__(256) void k_norm(float* __restrict__ out,
                                              const float* __restrict__ stats,
                                              const float* __restrict__ gamma,
                                              const float* __restrict__ beta){
  int idx4 = (blockIdx.x*256 + threadIdx.x)*4;
  int o = (idx4 >> 15) & 255;
  int b = idx4 >> 23;
  int bg = b*32 + (o >> 3);
  const float inv_n = 1.0f/262144.0f;
  float mean = stats[bg*2+0] * inv_n;
  float var  = stats[bg*2+1] * inv_n - mean*mean;
  float sc = rsqrtf(var + 1e-5f);
  float ga = gamma[o], be = beta[o];
  float4 v = *(float4*)(out + idx4);
  float t0 = (v.x - mean)*sc*ga + be;
  float t1 = (v.y - mean)*sc*ga + be;
  float t2 = (v.z - mean)*sc*ga + be;
  float t3 = (v.w - mean)*sc*ga + be;
  const float ISQ2 = 0.70710678118654752f;
  v.x = 0.5f*t0*(1.0f + erff(t0*ISQ2));
  v.y = 0.5f*t1*(1.0f + erff(t1*ISQ2));
  v.z = 0.5f*t2*(1.0f + erff(t2*ISQ2));
  v.w = 0.5f*t3*(1.0f + erff(t3*ISQ2));
  *(float4*)(out + idx4) = v;
}

extern "C" void kernel_launch(void* const* d_in, const int* in_sizes, int n_in,
                              void* d_out, int out_size, void* d_ws, size_t ws_size,
                              hipStream_t stream){
  const float* x      = (const float*)d_in[0];
  const float* conv_w = (const float*)d_in[1];
  const float* conv_b = (const float*)d_in[2];
  const float* gamma  = (const float*)d_in[3];
  const float* beta   = (const float*)d_in[4];
  const float* wmat   = (const float*)d_in[5];
  const float* pct    = (const float*)d_in[6];
  float* ws  = (float*)d_ws;
  float* F     = ws + OFF_F;
  float* Fi    = ws + OFF_FI;
  float* stats = ws + OFF_ST;
  float* Xpl   = ws + OFF_X;     // X planes [256][131072]
  float* gpl   = ws + OFF_X;     // g planes [256][65536] (reuses X region; X dead after leg1)
  float* flm   = ws + OFF_Y2;    // flm planes [256][65536]
  float* ybuf  = ws + OFF_Y2;    // y [65536][256] (reuses flm region; flm dead after leg2)
  float* out = (float*)d_out;

  k_tables<<<769, 256, 0, stream>>>(ws);
  k_dft  <<<dim3(1024,2),   256, 0, stream>>>(x, F, Xpl);
  k_leg1 <<<dim3(8,2,256),  256, 0, stream>>>(Xpl, wmat, flm);
  k_leg2 <<<dim3(8,2,256),  256, 0, stream>>>(flm, pct, gpl);
  k_idft <<<dim3(512,2),    256, 0, stream>>>(gpl, Fi, ybuf);
  k_conv <<<dim3(256,2,2),  256, 0, stream>>>(ybuf, conv_w, conv_b, out);
  k_stats<<<dim3(32,64),    256, 0, stream>>>(out, stats);
  k_norm <<<16384,          256, 0, stream>>>(out, stats, gamma, beta);
}

// Round 2
// 699.136 us; speedup vs baseline: 1.5833x; 1.5833x over previous
//
#include <hip/hip_runtime.h>
#include <math.h>

// x:[2,256,256,512] f32 -> out:[2,256,128,256] f32
// Planes p = 2m (Re), 2m+1 (Im), m=0..127 (m=128 slice of wmat_hi is identically 0).

#define ROWS_HI 131072   // B*C*H_HI
#define ROWS_LO 65536    // B*C*H_LO

// ws byte offsets
#define B_FT    0LL           // F_T  bf16 [256 p][512 w]      262144 B
#define B_FIT   262144LL      // Fi_T bf16 [256 w'][256 p]     131072 B
#define B_WM    393216LL      // wmat bf16 [128 m][128 l][256 k]  8388608 B
#define B_PCT   8781824LL     // pctT bf16 [128 m][128 k'][128 l] 4194304 B
#define B_STATS 12976128LL    // 128 floats
#define B_R1    12976640LL    // 67108864 B region: Xbf -> g -> y
#define B_R2    80085504LL    // 67108864 B region: flm -> gT -> yT
// total 147,194,368 B (< R1's 202 MB which fit)

typedef __attribute__((ext_vector_type(8))) short bf16x8;
typedef __attribute__((ext_vector_type(8))) unsigned short ushort8;
typedef __attribute__((ext_vector_type(4))) unsigned short ushort4v;
typedef __attribute__((ext_vector_type(4))) float f32x4;

__device__ inline unsigned short f2bf(float f){
  unsigned int u = __float_as_uint(f);
  unsigned int r = u + 0x7FFFu + ((u >> 16) & 1u);
  return (unsigned short)(r >> 16);
}
__device__ inline float bf2f(unsigned short h){
  return __uint_as_float(((unsigned int)h) << 16);
}

// ---------------- tables: DFT/iDFT twiddles (bf16, transposed) + zero stats ----
__global__ __launch_bounds__(256) void k_tables(unsigned char* __restrict__ ws){
  unsigned short* FT  = (unsigned short*)(ws + B_FT);
  unsigned short* FIT = (unsigned short*)(ws + B_FIT);
  float* stats = (float*)(ws + B_STATS);
  int idx = blockIdx.x*256 + threadIdx.x;
  if (idx < 131072){            // F_T[p][w], p=idx>>9, w=idx&511
    int p = idx >> 9, w = idx & 511, m = p >> 1;
    int pr = (m*w) & 511;
    float ang = (float)pr * (float)(2.0*M_PI/512.0);
    float s, c; sincosf(ang, &s, &c);
    const float S = (float)(2.0*M_PI/512.0);
    FT[idx] = f2bf((p & 1) ? (-S*s) : (S*c));
  }
  int i2 = idx - 131072;
  if (i2 >= 0 && i2 < 65536){   // Fi_T[w][p], w=i2>>8, p=i2&255
    int w = i2 >> 8, p = i2 & 255, m = p >> 1;
    float eps = (m == 0) ? 1.f : 2.f;
    int pr = (m*w) & 255;
    float ang = (float)pr * (float)(2.0*M_PI/256.0);
    float s, c; sincosf(ang, &s, &c);
    FIT[i2] = f2bf((p & 1) ? (-eps*s) : (eps*c));
  }
  int i3 = idx - (131072 + 65536);
  if (i3 >= 0 && i3 < 128) stats[i3] = 0.f;
}

// ---------------- prep: wmat -> bf16 (same layout), pct -> bf16 transposed ----
__global__ __launch_bounds__(256) void k_prep(const float* __restrict__ wmat,
                                              const float* __restrict__ pct,
                                              unsigned char* __restrict__ ws){
  unsigned short* WM = (unsigned short*)(ws + B_WM);
  unsigned short* PT = (unsigned short*)(ws + B_PCT);
  int idx = blockIdx.x*256 + threadIdx.x;
  if (idx < 4194304){
    WM[idx] = f2bf(wmat[idx]);            // [m][l][k] direct, m<128
  } else {
    int j = idx - 4194304;                // pctT[m][kp][l] = pct[m][l][kp]
    if (j < 2097152){
      int m = j >> 14, kp = (j >> 7) & 127, l = j & 127;
      PT[j] = f2bf(pct[m*16384 + l*128 + kp]);
    }
  }
}

// ---------------- MFMA GEMM template -----------------------------------------
// C[M][N] = A[M][K] * B_T[N][K]^T ; BM=BN=128, BK=32, 256 threads (4 waves,
// each owns a 64x64 quadrant as 4x4 mfma 16x16x32 tiles).
// AMODE 0: A fp32, split hi/lo bf16 in-kernel (2 mfma chains -> ~fp32 accuracy)
// AMODE 1: A bf16 single (pre-quantized)
// CMODE 0: row-major fp32 store (+optional bias[row])
// CMODE 1: transposed bf16 store C_T[col][row] (plane-major, single bf16)
template<int AMODE, int CMODE, bool BIAS>
__global__ __launch_bounds__(256) void k_gemm(
    const float* __restrict__ Af,
    const unsigned short* __restrict__ Abf,
    const unsigned short* __restrict__ Bt,
    float* __restrict__ Cf,
    unsigned short* __restrict__ Cbf,
    const float* __restrict__ bias,
    int ldA, int ldB, int ldC, int ksteps,
    long long sA, long long sB, int bzsh, long long sC)
{
  __shared__ unsigned short Ah[128][40];
  __shared__ unsigned short Al[128][40];
  __shared__ unsigned short Bs[128][40];
  const int tid = threadIdx.x;
  const int z = blockIdx.z;
  const long long offA = (long long)z * sA;
  const long long offB = (long long)(z >> bzsh) * sB;
  const long long offC = (long long)z * sC;
  const int row0 = blockIdx.x * 128;
  const int n0   = blockIdx.y * 128;
  const int lane = tid & 63;
  const int wv = tid >> 6;
  const int wm = wv >> 1, wn = wv & 1;
  const int fr = lane & 15, q = lane >> 4;
  const int ms = tid >> 1, half = tid & 1;

  f32x4 acc[4][4];
#pragma unroll
  for (int i=0;i<4;++i)
#pragma unroll
    for (int j=0;j<4;++j) acc[i][j] = (f32x4){0.f,0.f,0.f,0.f};

  for (int ks = 0; ks < ksteps; ++ks){
    const int k0 = ks * 32;
    if (AMODE == 0){
      const float* s = Af + offA + (long long)(row0 + ms) * ldA + k0 + half*16;
      float vv[16];
      *(float4*)(vv+0)  = *(const float4*)(s+0);
      *(float4*)(vv+4)  = *(const float4*)(s+4);
      *(float4*)(vv+8)  = *(const float4*)(s+8);
      *(float4*)(vv+12) = *(const float4*)(s+12);
      ushort8 H0, H1, L0, L1;
#pragma unroll
      for (int j=0;j<8;++j){
        unsigned short h = f2bf(vv[j]);
        H0[j] = h; L0[j] = f2bf(vv[j] - bf2f(h));
        unsigned short h2 = f2bf(vv[8+j]);
        H1[j] = h2; L1[j] = f2bf(vv[8+j] - bf2f(h2));
      }
      *(ushort8*)&Ah[ms][half*16]   = H0;
      *(ushort8*)&Ah[ms][half*16+8] = H1;
      *(ushort8*)&Al[ms][half*16]   = L0;
      *(ushort8*)&Al[ms][half*16+8] = L1;
    } else {
      const unsigned short* s = Abf + offA + (long long)(row0 + ms) * ldA + k0 + half*16;
      *(ushort8*)&Ah[ms][half*16]   = *(const ushort8*)(s);
      *(ushort8*)&Ah[ms][half*16+8] = *(const ushort8*)(s+8);
    }
    {
      const unsigned short* s = Bt + offB + (long long)(n0 + ms) * ldB + k0 + half*16;
      *(ushort8*)&Bs[ms][half*16]   = *(const ushort8*)(s);
      *(ushort8*)&Bs[ms][half*16+8] = *(const ushort8*)(s+8);
    }
    __syncthreads();
    bf16x8 ah[4], al[4];
#pragma unroll
    for (int mt=0;mt<4;++mt){
      ah[mt] = *(const bf16x8*)&Ah[wm*64+mt*16+fr][q*8];
      if (AMODE == 0) al[mt] = *(const bf16x8*)&Al[wm*64+mt*16+fr][q*8];
    }
#pragma unroll
    for (int nt=0;nt<4;++nt){
      bf16x8 bb = *(const bf16x8*)&Bs[wn*64+nt*16+fr][q*8];
#pragma unroll
      for (int mt=0;mt<4;++mt){
        if (AMODE == 0)
          acc[mt][nt] = __builtin_amdgcn_mfma_f32_16x16x32_bf16(al[mt], bb, acc[mt][nt], 0,0,0);
        acc[mt][nt] = __builtin_amdgcn_mfma_f32_16x16x32_bf16(ah[mt], bb, acc[mt][nt], 0,0,0);
      }
    }
    __syncthreads();
  }

  if (CMODE == 0){
#pragma unroll
    for (int mt=0;mt<4;++mt){
      int row = row0 + wm*64 + mt*16 + q*4;
      float bv0=0.f,bv1=0.f,bv2=0.f,bv3=0.f;
      if (BIAS){ bv0=bias[row]; bv1=bias[row+1]; bv2=bias[row+2]; bv3=bias[row+3]; }
#pragma unroll
      for (int nt=0;nt<4;++nt){
        int col = n0 + wn*64 + nt*16 + fr;
        float* dst = Cf + offC + (long long)row * ldC + col;
        dst[0]                 = acc[mt][nt][0] + bv0;
        dst[(long long)ldC]    = acc[mt][nt][1] + bv1;
        dst[(long long)ldC*2]  = acc[mt][nt][2] + bv2;
        dst[(long long)ldC*3]  = acc[mt][nt][3] + bv3;
      }
    }
  } else {
#pragma unroll
    for (int nt=0;nt<4;++nt){
      int colp = n0 + wn*64 + nt*16 + fr;
#pragma unroll
      for (int mt=0;mt<4;++mt){
        int rowb = row0 + wm*64 + mt*16 + q*4;
        ushort4v h;
        h[0] = f2bf(acc[mt][nt][0]);
        h[1] = f2bf(acc[mt][nt][1]);
        h[2] = f2bf(acc[mt][nt][2]);
        h[3] = f2bf(acc[mt][nt][3]);
        *(ushort4v*)&Cbf[(long long)colp * ldC + rowb] = h;
      }
    }
  }
}

// ---------------- transpose g[256][65536] f32 -> gT[65536][256] f32 -----------
__global__ __launch_bounds__(256) void k_tr(const float* __restrict__ g,
                                            float* __restrict__ gT){
  __shared__ float t[64][65];
  const int r0 = blockIdx.x * 64;
  const int p0 = blockIdx.y * 64;
  const int tr = threadIdx.x & 15, tc = threadIdx.x >> 4;
#pragma unroll
  for (int i=0;i<4;++i){
    int pl = tc + i*16;
    float4 v = *(const float4*)(g + (long long)(p0+pl)*ROWS_LO + r0 + tr*4);
    t[pl][tr*4+0]=v.x; t[pl][tr*4+1]=v.y; t[pl][tr*4+2]=v.z; t[pl][tr*4+3]=v.w;
  }
  __syncthreads();
#pragma unroll
  for (int i=0;i<4;++i){
    int rl = tc + i*16;
    float4 w;
    w.x = t[tr*4+0][rl]; w.y = t[tr*4+1][rl]; w.z = t[tr*4+2][rl]; w.w = t[tr*4+3][rl];
    *(float4*)(gT + (long long)(r0+rl)*256 + p0 + tr*4) = w;
  }
}

// ---------------- transpose y[b][256 c][32768 s] f32 -> yT[b][s][c] bf16 ------
__global__ __launch_bounds__(256) void k_tr2(const float* __restrict__ y,
                                             unsigned short* __restrict__ yT){
  __shared__ float t[64][65];
  const int s0 = blockIdx.x * 64;
  const int c0 = blockIdx.y * 64;
  const int b  = blockIdx.z;
  const int tr = threadIdx.x & 15, tc = threadIdx.x >> 4;
#pragma unroll
  for (int i=0;i<4;++i){
    int cl = tc + i*16;
    float4 v = *(const float4*)(y + (long long)b*8388608 + (long long)(c0+cl)*32768 + s0 + tr*4);
    t[cl][tr*4+0]=v.x; t[cl][tr*4+1]=v.y; t[cl][tr*4+2]=v.z; t[cl][tr*4+3]=v.w;
  }
  __syncthreads();
#pragma unroll
  for (int i=0;i<4;++i){
    int sl = tc + i*16;
    ushort4v w;
    w[0]=f2bf(t[tr*4+0][sl]); w[1]=f2bf(t[tr*4+1][sl]);
    w[2]=f2bf(t[tr*4+2][sl]); w[3]=f2bf(t[tr*4+3][sl]);
    *(ushort4v*)(yT + (long long)b*8388608 + (long long)(s0+sl)*256 + c0 + tr*4) = w;
  }
}

// ---------------- GroupNorm stats --------------------------------------------
__global__ __launch_bounds__(256) void k_stats(const float* __restrict__ h,
                                               float* __restrict__ stats){
  const int bg = blockIdx.y;
  const int j  = blockIdx.x;
  const int t  = threadIdx.x;
  const float* base = h + (long long)bg*262144 + j*8192;
  float s = 0.f, ss = 0.f;
#pragma unroll
  for (int i=0;i<8;++i){
    float4 v = *(const float4*)(base + i*1024 + t*4);
    s  += v.x + v.y + v.z + v.w;
    ss += v.x*v.x + v.y*v.y + v.z*v.z + v.w*v.w;
  }
#pragma unroll
  for (int off=32; off>0; off>>=1){
    s  += __shfl_down(s, off, 64);
    ss += __shfl_down(ss, off, 64);
  }
  __shared__ float red[8];
  int wid = t >> 6;
  if ((t & 63) == 0){ red[wid*2] = s; red[wid*2+1] = ss; }
  __syncthreads();
  if (t == 0){
    float S  = red[0]+red[2]+red[4]+red[6];
    float SS = red[1]+red[3]+red[5]+red[7];
    atomicAdd(&stats[bg*2+0], S);
    atomicAdd(&stats[bg*2+1], SS);
  }
}

// ---------------- normalize + affine + exact GELU ----------------------------
__global__ __launch_bounds__(256) void k_norm(float* __restrict__ out,
                                              const float* __restrict__ stats,
                                              const float* __restrict__ gamma,
                                              const float* __restrict__ beta){
  long long idx4 = ((long long)blockIdx.x*256 + threadIdx.x)*4;
  int o = (int)((idx4 >> 15) & 255);
  int b = (int)(idx4 >> 23);
  int bg = b*32 + (o >> 3);
  const float inv_n = 1.0f/262144.0f;
  float mean = stats[bg*2+0] * inv_n;
  float var  = stats[bg*2+1] * inv_n - mean*mean;
  float sc = rsqrtf(var + 1e-5f);
  float ga = gamma[o], be = beta[o];
  float4 v = *(float4*)(out + idx4);
  float t0 = (v.x - mean)*sc*ga + be;
  float t1 = (v.y - mean)*sc*ga + be;
  float t2 = (v.z - mean)*sc*ga + be;
  float t3 = (v.w - mean)*sc*ga + be;
  const float ISQ2 = 0.70710678118654752f;
  v.x = 0.5f*t0*(1.0f + erff(t0*ISQ2));
  v.y = 0.5f*t1*(1.0f + erff(t1*ISQ2));
  v.z = 0.5f*t2*(1.0f + erff(t2*ISQ2));
  v.w = 0.5f*t3*(1.0f + erff(t3*ISQ2));
  *(float4*)(out + idx4) = v;
}

extern "C" void kernel_launch(void* const* d_in, const int* in_sizes, int n_in,
                              void* d_out, int out_size, void* d_ws, size_t ws_size,
                              hipStream_t stream){
  const float* x      = (const float*)d_in[0];
  const float* conv_w = (const float*)d_in[1];
  const float* conv_b = (const float*)d_in[2];
  const float* gamma  = (const float*)d_in[3];
  const float* beta   = (const float*)d_in[4];
  const float* wmat   = (const float*)d_in[5];
  const float* pct    = (const float*)d_in[6];
  unsigned char* ws = (unsigned char*)d_ws;

  unsigned short* FT   = (unsigned short*)(ws + B_FT);
  unsigned short* FIT  = (unsigned short*)(ws + B_FIT);
  unsigned short* WM   = (unsigned short*)(ws + B_WM);
  unsigned short* PT   = (unsigned short*)(ws + B_PCT);
  float*          stats= (float*)(ws + B_STATS);
  unsigned short* Xbf  = (unsigned short*)(ws + B_R1);  // [256 p][131072 row] bf16
  float*          g    = (float*)(ws + B_R1);           // [256 p][65536 row] (Xbf dead)
  float*          y    = (float*)(ws + B_R1);           // [bc*k'][256 w'] (g dead)
  float*          flm  = (float*)(ws + B_R2);           // [256 p][512 bc][128 l]
  float*          gT   = (float*)(ws + B_R2);           // [65536 row][256 p] (flm dead)
  unsigned short* yT   = (unsigned short*)(ws + B_R2);  // [b][32768 s][256 c] bf16 (gT dead)
  float* out = (float*)d_out;

  k_tables<<<769, 256, 0, stream>>>(ws);
  k_prep  <<<24576, 256, 0, stream>>>(wmat, pct, ws);

  // DFT: A=x f32 split [131072x512], B=F_T, C -> Xbf (trans bf16, plane-major)
  k_gemm<0,1,false><<<dim3(1024,2,1), 256, 0, stream>>>(
      x, nullptr, FT, nullptr, Xbf, nullptr, 512, 512, ROWS_HI, 16, 0, 0, 0, 0);
  // Leg1: per plane p: A=Xbf[p] bf16 [512x256], B=wmat_bf[m], C=flm f32
  k_gemm<1,0,false><<<dim3(4,1,256), 256, 0, stream>>>(
      nullptr, Xbf, WM, flm, nullptr, nullptr, 256, 256, 128, 8,
      (long long)ROWS_HI, 32768LL, 1, (long long)ROWS_LO);
  // Leg2: per plane p: A=flm[p] f32 split [512x128], B=pctT[m], C=g f32
  k_gemm<0,0,false><<<dim3(4,1,256), 256, 0, stream>>>(
      flm, nullptr, PT, g, nullptr, nullptr, 128, 128, 128, 4,
      (long long)ROWS_LO, 16384LL, 1, (long long)ROWS_LO);
  // transpose g -> gT
  k_tr<<<dim3(1024,4), 256, 0, stream>>>(g, gT);
  // iDFT: A=gT f32 split [65536x256], B=Fi_T, C=y f32 [65536x256]
  k_gemm<0,0,false><<<dim3(512,2,1), 256, 0, stream>>>(
      gT, nullptr, FIT, y, nullptr, nullptr, 256, 256, 256, 8, 0, 0, 0, 0);
  // transpose+quantize y -> yT bf16
  k_tr2<<<dim3(512,4,2), 256, 0, stream>>>(y, yT);
  // Conv: per b: A=conv_w f32 split [256x256], B=yT[b] [32768x256], C=out +bias
  k_gemm<0,0,true><<<dim3(2,256,2), 256, 0, stream>>>(
      conv_w, nullptr, yT, out, nullptr, conv_b, 256, 256, 32768, 8,
      0, 8388608LL, 0, 8388608LL);

  k_stats<<<dim3(32,64), 256, 0, stream>>>(out, stats);
  k_norm <<<16384, 256, 0, stream>>>(out, stats, gamma, beta);
}

// Round 3
// 670.517 us; speedup vs baseline: 1.6509x; 1.0427x over previous
//
#include <hip/hip_runtime.h>
#include <math.h>

// x:[2,256,256,512] f32 -> out:[2,256,128,256] f32
// Planes p = 2m (Re), 2m+1 (Im), m=0..127 (m=128 slice of wmat_hi is identically 0).

#define ROWS_HI 131072   // B*C*H_HI
#define ROWS_LO 65536    // B*C*H_LO

// ws byte offsets
#define B_FT    0LL           // F_T  bf16 [256 p][512 w]
#define B_FIT   262144LL      // Fi_T bf16 [256 w'][256 p]
#define B_WM    393216LL      // wmat bf16 [128 m][128 l][256 k]
#define B_PCT   8781824LL     // pctT bf16 [128 m][128 k'][128 l]
#define B_WB    12976128LL    // conv_w bf16 [256 o][256 c]
#define B_STATS 13107200LL    // 128 floats
#define B_R1    13107712LL    // 64 MB region: Xbf(64MB bf16) -> gb(32MB bf16) -> y(64MB f32)
#define B_R2    80216576LL    // 32 MB region: flmb -> gTb -> yT (all bf16)
// total 113,771,008 B

typedef __attribute__((ext_vector_type(8))) short bf16x8;
typedef __attribute__((ext_vector_type(8))) unsigned short ushort8;
typedef __attribute__((ext_vector_type(4))) unsigned short ushort4v;
typedef __attribute__((ext_vector_type(4))) float f32x4;

__device__ inline unsigned short f2bf(float f){
  unsigned int u = __float_as_uint(f);
  unsigned int r = u + 0x7FFFu + ((u >> 16) & 1u);
  return (unsigned short)(r >> 16);
}

// ---------------- tables: DFT/iDFT twiddles (bf16) + zero stats ---------------
__global__ __launch_bounds__(256) void k_tables(unsigned char* __restrict__ ws){
  unsigned short* FT  = (unsigned short*)(ws + B_FT);
  unsigned short* FIT = (unsigned short*)(ws + B_FIT);
  float* stats = (float*)(ws + B_STATS);
  int idx = blockIdx.x*256 + threadIdx.x;
  if (idx < 131072){            // F_T[p][w]
    int p = idx >> 9, w = idx & 511, m = p >> 1;
    int pr = (m*w) & 511;
    float ang = (float)pr * (float)(2.0*M_PI/512.0);
    float s, c; sincosf(ang, &s, &c);
    const float S = (float)(2.0*M_PI/512.0);
    FT[idx] = f2bf((p & 1) ? (-S*s) : (S*c));
  }
  int i2 = idx - 131072;
  if (i2 >= 0 && i2 < 65536){   // Fi_T[w'][p]
    int w = i2 >> 8, p = i2 & 255, m = p >> 1;
    float eps = (m == 0) ? 1.f : 2.f;
    int pr = (m*w) & 255;
    float ang = (float)pr * (float)(2.0*M_PI/256.0);
    float s, c; sincosf(ang, &s, &c);
    FIT[i2] = f2bf((p & 1) ? (-eps*s) : (eps*c));
  }
  int i3 = idx - (131072 + 65536);
  if (i3 >= 0 && i3 < 128) stats[i3] = 0.f;
}

// ------- prep: wmat->bf16, pct->bf16 transposed, conv_w->bf16 ----------------
__global__ __launch_bounds__(256) void k_prep(const float* __restrict__ wmat,
                                              const float* __restrict__ pct,
                                              const float* __restrict__ Wc,
                                              unsigned char* __restrict__ ws){
  unsigned short* WM = (unsigned short*)(ws + B_WM);
  unsigned short* PT = (unsigned short*)(ws + B_PCT);
  unsigned short* WB = (unsigned short*)(ws + B_WB);
  int idx = blockIdx.x*256 + threadIdx.x;
  if (idx < 4194304){
    WM[idx] = f2bf(wmat[idx]);            // [m][l][k] direct, m<128
  } else if (idx < 6291456){
    int j = idx - 4194304;                // pctT[m][kp][l] = pct[m][l][kp]
    int m = j >> 14, kp = (j >> 7) & 127, l = j & 127;
    PT[j] = f2bf(pct[m*16384 + l*128 + kp]);
  } else if (idx < 6356992){
    int j = idx - 6291456;
    WB[j] = f2bf(Wc[j]);                  // [o][c]
  }
}

// ---------------- MFMA GEMM template -----------------------------------------
// C[M][N] = A[M][K] * B_T[N][K]^T ; BM=MT*32, BN=NT*32, BK=32, 256 thr
// (2x2 waves, each wave (MT*16)x(NT*16) via 16x16x32 bf16 MFMA).
// AMODE 0: A fp32 -> quantize to bf16 in staging (BM must be 128)
// AMODE 1: A bf16 (pre-quantized)
// CMODE 0: row-major fp32 store (+optional bias[row])
// CMODE 1: transposed bf16 store C_T[col][row]
// CMODE 2: row-major bf16 store
// SKIP 1: skip nt-tiles with col_max < m (leg1, cols=l) ; SKIP 2: k-loop starts
//         at (m>>5) (leg2, k=l).  m = blockIdx.z>>1.
template<int AMODE, int CMODE, bool BIAS, int MT, int NT, int SKIP>
__global__ __launch_bounds__(256) void k_gemm(
    const float* __restrict__ Af,
    const unsigned short* __restrict__ Abf,
    const unsigned short* __restrict__ Bt,
    float* __restrict__ Cf,
    unsigned short* __restrict__ Cbf,
    const float* __restrict__ bias,
    int ldA, int ldB, int ldC, int ksteps,
    long long sA, long long sB, int bzsh, long long sC)
{
  constexpr int BM = MT*32;
  constexpr int BN = NT*32;
  __shared__ unsigned short As[BM][40];
  __shared__ unsigned short Bs[BN][40];
  const int tid = threadIdx.x;
  const int z = blockIdx.z;
  const int m = z >> 1;
  const long long offA = (long long)z * sA;
  const long long offB = (long long)(z >> bzsh) * sB;
  const long long offC = (long long)z * sC;
  const int row0 = blockIdx.x * BM;
  const int n0   = blockIdx.y * BN;
  const int lane = tid & 63;
  const int wv = tid >> 6;
  const int wm = wv >> 1, wn = wv & 1;
  const int fr = lane & 15, q = lane >> 4;

  f32x4 acc[MT][NT];
#pragma unroll
  for (int i=0;i<MT;++i)
#pragma unroll
    for (int j=0;j<NT;++j) acc[i][j] = (f32x4){0.f,0.f,0.f,0.f};

  int ks0 = (SKIP == 2) ? (m >> 5) : 0;
  for (int ks = ks0; ks < ksteps; ++ks){
    const int k0 = ks * 32;
    // ---- stage A
    if (AMODE == 0){
      const int row = tid >> 1, half = tid & 1;
      const float* s = Af + offA + (long long)(row0 + row) * ldA + k0 + half*16;
      float vv[16];
      *(float4*)(vv+0)  = *(const float4*)(s+0);
      *(float4*)(vv+4)  = *(const float4*)(s+4);
      *(float4*)(vv+8)  = *(const float4*)(s+8);
      *(float4*)(vv+12) = *(const float4*)(s+12);
      ushort8 H0, H1;
#pragma unroll
      for (int j=0;j<8;++j){ H0[j] = f2bf(vv[j]); H1[j] = f2bf(vv[8+j]); }
      *(ushort8*)&As[row][half*16]   = H0;
      *(ushort8*)&As[row][half*16+8] = H1;
    } else if (BM == 256){
      const unsigned short* s = Abf + offA + (long long)(row0 + tid) * ldA + k0;
      *(ushort8*)&As[tid][0]  = *(const ushort8*)(s);
      *(ushort8*)&As[tid][8]  = *(const ushort8*)(s+8);
      *(ushort8*)&As[tid][16] = *(const ushort8*)(s+16);
      *(ushort8*)&As[tid][24] = *(const ushort8*)(s+24);
    } else {
      const int row = tid >> 1, half = tid & 1;
      const unsigned short* s = Abf + offA + (long long)(row0 + row) * ldA + k0 + half*16;
      *(ushort8*)&As[row][half*16]   = *(const ushort8*)(s);
      *(ushort8*)&As[row][half*16+8] = *(const ushort8*)(s+8);
    }
    // ---- stage B
    if (BN == 256){
      const unsigned short* s = Bt + offB + (long long)(n0 + tid) * ldB + k0;
      *(ushort8*)&Bs[tid][0]  = *(const ushort8*)(s);
      *(ushort8*)&Bs[tid][8]  = *(const ushort8*)(s+8);
      *(ushort8*)&Bs[tid][16] = *(const ushort8*)(s+16);
      *(ushort8*)&Bs[tid][24] = *(const ushort8*)(s+24);
    } else {
      const int row = tid >> 1, half = tid & 1;
      const unsigned short* s = Bt + offB + (long long)(n0 + row) * ldB + k0 + half*16;
      *(ushort8*)&Bs[row][half*16]   = *(const ushort8*)(s);
      *(ushort8*)&Bs[row][half*16+8] = *(const ushort8*)(s+8);
    }
    __syncthreads();
    bf16x8 ah[MT];
#pragma unroll
    for (int mt=0;mt<MT;++mt)
      ah[mt] = *(const bf16x8*)&As[wm*(MT*16)+mt*16+fr][q*8];
#pragma unroll
    for (int nt=0;nt<NT;++nt){
      if (SKIP == 1 && (wn*(NT*16) + nt*16 + 16 <= m)) continue;
      bf16x8 bb = *(const bf16x8*)&Bs[wn*(NT*16)+nt*16+fr][q*8];
#pragma unroll
      for (int mt=0;mt<MT;++mt)
        acc[mt][nt] = __builtin_amdgcn_mfma_f32_16x16x32_bf16(ah[mt], bb, acc[mt][nt], 0,0,0);
    }
    __syncthreads();
  }

  if (CMODE == 0){
#pragma unroll
    for (int mt=0;mt<MT;++mt){
      int row = row0 + wm*(MT*16) + mt*16 + q*4;
      float bv0=0.f,bv1=0.f,bv2=0.f,bv3=0.f;
      if (BIAS){ bv0=bias[row]; bv1=bias[row+1]; bv2=bias[row+2]; bv3=bias[row+3]; }
#pragma unroll
      for (int nt=0;nt<NT;++nt){
        int col = n0 + wn*(NT*16) + nt*16 + fr;
        float* dst = Cf + offC + (long long)row * ldC + col;
        dst[0]                = acc[mt][nt][0] + bv0;
        dst[(long long)ldC]   = acc[mt][nt][1] + bv1;
        dst[(long long)ldC*2] = acc[mt][nt][2] + bv2;
        dst[(long long)ldC*3] = acc[mt][nt][3] + bv3;
      }
    }
  } else if (CMODE == 1){
#pragma unroll
    for (int nt=0;nt<NT;++nt){
      int colp = n0 + wn*(NT*16) + nt*16 + fr;
#pragma unroll
      for (int mt=0;mt<MT;++mt){
        int rowb = row0 + wm*(MT*16) + mt*16 + q*4;
        ushort4v h;
        h[0] = f2bf(acc[mt][nt][0]);
        h[1] = f2bf(acc[mt][nt][1]);
        h[2] = f2bf(acc[mt][nt][2]);
        h[3] = f2bf(acc[mt][nt][3]);
        *(ushort4v*)&Cbf[offC + (long long)colp * ldC + rowb] = h;
      }
    }
  } else {
#pragma unroll
    for (int mt=0;mt<MT;++mt){
      int row = row0 + wm*(MT*16) + mt*16 + q*4;
#pragma unroll
      for (int nt=0;nt<NT;++nt){
        int col = n0 + wn*(NT*16) + nt*16 + fr;
        unsigned short* dst = Cbf + offC + (long long)row * ldC + col;
        dst[0]      = f2bf(acc[mt][nt][0]);
        dst[ldC]    = f2bf(acc[mt][nt][1]);
        dst[ldC*2]  = f2bf(acc[mt][nt][2]);
        dst[ldC*3]  = f2bf(acc[mt][nt][3]);
      }
    }
  }
}

// ------- transpose bf16 g[256 p][65536 r] -> gT[65536 r][256 p] ---------------
__global__ __launch_bounds__(256) void k_trb(const unsigned short* __restrict__ g,
                                             unsigned short* __restrict__ gT){
  __shared__ unsigned short t[64][68];
  const int r0 = blockIdx.x * 64;
  const int p0 = blockIdx.y * 64;
  const int tr = threadIdx.x & 15, tc = threadIdx.x >> 4;
#pragma unroll
  for (int i=0;i<4;++i){
    int pl = tc + i*16;
    ushort4v v = *(const ushort4v*)(g + (long long)(p0+pl)*ROWS_LO + r0 + tr*4);
    *(ushort4v*)&t[pl][tr*4] = v;
  }
  __syncthreads();
#pragma unroll
  for (int i=0;i<4;++i){
    int rl = tc + i*16;
    ushort4v w;
    w[0]=t[tr*4+0][rl]; w[1]=t[tr*4+1][rl]; w[2]=t[tr*4+2][rl]; w[3]=t[tr*4+3][rl];
    *(ushort4v*)(gT + (long long)(r0+rl)*256 + p0 + tr*4) = w;
  }
}

// ------- transpose y[b][256 c][32768 s] f32 -> yT[b][s][c] bf16 ---------------
__global__ __launch_bounds__(256) void k_tr2(const float* __restrict__ y,
                                             unsigned short* __restrict__ yT){
  __shared__ float t[64][65];
  const int s0 = blockIdx.x * 64;
  const int c0 = blockIdx.y * 64;
  const int b  = blockIdx.z;
  const int tr = threadIdx.x & 15, tc = threadIdx.x >> 4;
#pragma unroll
  for (int i=0;i<4;++i){
    int cl = tc + i*16;
    float4 v = *(const float4*)(y + (long long)b*8388608 + (long long)(c0+cl)*32768 + s0 + tr*4);
    t[cl][tr*4+0]=v.x; t[cl][tr*4+1]=v.y; t[cl][tr*4+2]=v.z; t[cl][tr*4+3]=v.w;
  }
  __syncthreads();
#pragma unroll
  for (int i=0;i<4;++i){
    int sl = tc + i*16;
    ushort4v w;
    w[0]=f2bf(t[tr*4+0][sl]); w[1]=f2bf(t[tr*4+1][sl]);
    w[2]=f2bf(t[tr*4+2][sl]); w[3]=f2bf(t[tr*4+3][sl]);
    *(ushort4v*)(yT + (long long)b*8388608 + (long long)(s0+sl)*256 + c0 + tr*4) = w;
  }
}

// ---------------- GroupNorm stats --------------------------------------------
__global__ __launch_bounds__(256) void k_stats(const float* __restrict__ h,
                                               float* __restrict__ stats){
  const int bg = blockIdx.y;
  const int j  = blockIdx.x;
  const int t  = threadIdx.x;
  const float* base = h + (long long)bg*262144 + j*8192;
  float s = 0.f, ss = 0.f;
#pragma unroll
  for (int i=0;i<8;++i){
    float4 v = *(const float4*)(base + i*1024 + t*4);
    s  += v.x + v.y + v.z + v.w;
    ss += v.x*v.x + v.y*v.y + v.z*v.z + v.w*v.w;
  }
#pragma unroll
  for (int off=32; off>0; off>>=1){
    s  += __shfl_down(s, off, 64);
    ss += __shfl_down(ss, off, 64);
  }
  __shared__ float red[8];
  int wid = t >> 6;
  if ((t & 63) == 0){ red[wid*2] = s; red[wid*2+1] = ss; }
  __syncthreads();
  if (t == 0){
    float S  = red[0]+red[2]+red[4]+red[6];
    float SS = red[1]+red[3]+red[5]+red[7];
    atomicAdd(&stats[bg*2+0], S);
    atomicAdd(&stats[bg*2+1], SS);
  }
}

// ---------------- normalize + affine + exact GELU ----------------------------
__global__ __launch_bounds__(256) void k_norm(float* __restrict__ out,
                                              const float* __restrict__ stats,
                                              const float* __restrict__ gamma,
                                              const float* __restrict__ beta){
  long long idx4 = ((long long)blockIdx.x*256 + threadIdx.x)*4;
  int o = (int)((idx4 >> 15) & 255);
  int b = (int)(idx4 >> 23);
  int bg = b*32 + (o >> 3);
  const float inv_n = 1.0f/262144.0f;
  float mean = stats[bg*2+0] * inv_n;
  float var  = stats[bg*2+1] * inv_n - mean*mean;
  float sc = rsqrtf(var + 1e-5f);
  float ga = gamma[o], be = beta[o];
  float4 v = *(float4*)(out + idx4);
  float t0 = (v.x - mean)*sc*ga + be;
  float t1 = (v.y - mean)*sc*ga + be;
  float t2 = (v.z - mean)*sc*ga + be;
  float t3 = (v.w - mean)*sc*ga + be;
  const float ISQ2 = 0.70710678118654752f;
  v.x = 0.5f*t0*(1.0f + erff(t0*ISQ2));
  v.y = 0.5f*t1*(1.0f + erff(t1*ISQ2));
  v.z = 0.5f*t2*(1.0f + erff(t2*ISQ2));
  v.w = 0.5f*t3*(1.0f + erff(t3*ISQ2));
  *(float4*)(out + idx4) = v;
}

extern "C" void kernel_launch(void* const* d_in, const int* in_sizes, int n_in,
                              void* d_out, int out_size, void* d_ws, size_t ws_size,
                              hipStream_t stream){
  const float* x      = (const float*)d_in[0];
  const float* conv_w = (const float*)d_in[1];
  const float* conv_b = (const float*)d_in[2];
  const float* gamma  = (const float*)d_in[3];
  const float* beta   = (const float*)d_in[4];
  const float* wmat   = (const float*)d_in[5];
  const float* pct    = (const float*)d_in[6];
  unsigned char* ws = (unsigned char*)d_ws;

  unsigned short* FT   = (unsigned short*)(ws + B_FT);
  unsigned short* FIT  = (unsigned short*)(ws + B_FIT);
  unsigned short* WM   = (unsigned short*)(ws + B_WM);
  unsigned short* PT   = (unsigned short*)(ws + B_PCT);
  unsigned short* WB   = (unsigned short*)(ws + B_WB);
  float*          stats= (float*)(ws + B_STATS);
  unsigned short* Xbf  = (unsigned short*)(ws + B_R1);  // [256 p][131072] bf16
  unsigned short* gb   = (unsigned short*)(ws + B_R1);  // [256 p][65536] bf16 (Xbf dead)
  float*          y    = (float*)(ws + B_R1);           // [65536][256] f32 (gb dead)
  unsigned short* flmb = (unsigned short*)(ws + B_R2);  // [256 p][512 bc][128 l] bf16
  unsigned short* gTb  = (unsigned short*)(ws + B_R2);  // [65536][256 p] bf16 (flmb dead)
  unsigned short* yT   = (unsigned short*)(ws + B_R2);  // [b][32768 s][256 c] bf16 (gTb dead)
  float* out = (float*)d_out;

  k_tables<<<769, 256, 0, stream>>>(ws);
  k_prep  <<<24832, 256, 0, stream>>>(wmat, pct, conv_w, ws);

  // DFT: A=x f32 [131072x512] (quantized in staging), B=F_T, C->Xbf trans bf16
  k_gemm<0,1,false,4,8,0><<<dim3(1024,1,1), 256, 0, stream>>>(
      x, nullptr, FT, nullptr, Xbf, nullptr, 512, 512, ROWS_HI, 16, 0, 0, 0, 0);
  // Leg1: per plane: A=Xbf[p] [512x256], B=WM[m] [128lx256k], C=flmb bf16; skip l<m tiles
  k_gemm<1,2,false,4,4,1><<<dim3(4,1,256), 256, 0, stream>>>(
      nullptr, Xbf, WM, nullptr, flmb, nullptr, 256, 256, 128, 8,
      131072LL, 32768LL, 1, 65536LL);
  // Leg2: per plane: A=flmb[p] [512x128], B=PT[m] [128k'x128l], C=gb bf16; k-start m>>5
  k_gemm<1,2,false,4,4,2><<<dim3(4,1,256), 256, 0, stream>>>(
      nullptr, flmb, PT, nullptr, gb, nullptr, 128, 128, 128, 4,
      65536LL, 16384LL, 1, 65536LL);
  // transpose gb -> gTb
  k_trb<<<dim3(1024,4), 256, 0, stream>>>(gb, gTb);
  // iDFT: A=gTb [65536x256], B=Fi_T [256w'x256p], C=y f32
  k_gemm<1,0,false,4,8,0><<<dim3(512,1,1), 256, 0, stream>>>(
      nullptr, gTb, FIT, y, nullptr, nullptr, 256, 256, 256, 8, 0, 0, 0, 0);
  // transpose+quantize y -> yT bf16
  k_tr2<<<dim3(512,4,2), 256, 0, stream>>>(y, yT);
  // Conv: per b: A=WB [256x256], B=yT[b] [32768x256], C=out f32 +bias
  k_gemm<1,0,true,8,4,0><<<dim3(1,256,2), 256, 0, stream>>>(
      nullptr, WB, yT, out, nullptr, conv_b, 256, 256, 32768, 8,
      0, 8388608LL, 0, 8388608LL);

  k_stats<<<dim3(32,64), 256, 0, stream>>>(out, stats);
  k_norm <<<16384, 256, 0, stream>>>(out, stats, gamma, beta);
}